// Round 1
// baseline (95.406 us; speedup 1.0000x reference)
//
#include <hip/hip_runtime.h>
#include <hip/hip_bf16.h>
#include <math.h>

// Problem constants
#define C_CH   256
#define H_DIM  26
#define W_DIM  26
#define HW     (H_DIM * W_DIM)   // 676
#define N_BOX  128
#define OUTP   3
#define FEAT   (C_CH * OUTP * OUTP)  // 2304
#define H1     1024
#define H2     512

// ---------------------------------------------------------------------------
// Generic wave-per-row GEMV: out[r] = dot(M[r, 0:K], v[0:K]) ; M row-major.
// One 64-lane wave per output row; lanes stride K by 64 (coalesced).
// ---------------------------------------------------------------------------
__global__ void gemv_rows(const float* __restrict__ M, const float* __restrict__ v,
                          float* __restrict__ out, int R, int K) {
    int gwave = (blockIdx.x * blockDim.x + threadIdx.x) >> 6;
    int lane  = threadIdx.x & 63;
    if (gwave >= R) return;
    const float* row = M + (size_t)gwave * K;
    float s = 0.f;
    for (int k = lane; k < K; k += 64) s += row[k] * v[k];
    #pragma unroll
    for (int off = 32; off; off >>= 1) s += __shfl_down(s, off, 64);
    if (lane == 0) out[gwave] = s;
}

// ---------------------------------------------------------------------------
// cbias = dot(b1, v) + dot(b2, W3col) + b3    (single block, 256 threads)
// ---------------------------------------------------------------------------
__global__ void bias_collapse(const float* __restrict__ b1, const float* __restrict__ v,
                              const float* __restrict__ b2, const float* __restrict__ w3,
                              const float* __restrict__ b3, float* __restrict__ cb) {
    int t = threadIdx.x;
    float s = 0.f;
    for (int k = t; k < H1; k += 256) s += b1[k] * v[k];
    for (int k = t; k < H2; k += 256) s += b2[k] * w3[k];
    __shared__ float red[4];
    #pragma unroll
    for (int off = 32; off; off >>= 1) s += __shfl_down(s, off, 64);
    int lane = t & 63, wid = t >> 6;
    if (lane == 0) red[wid] = s;
    __syncthreads();
    if (t == 0) cb[0] = red[0] + red[1] + red[2] + red[3] + b3[0];
}

// ---------------------------------------------------------------------------
// Transpose x: [C, H*W] -> xT: [H*W, C] so channel is the fast axis.
// ---------------------------------------------------------------------------
__global__ void transpose_x(const float* __restrict__ x, float* __restrict__ xT) {
    int p = blockIdx.x;      // pixel 0..675
    int c = threadIdx.x;     // channel 0..255
    xT[p * C_CH + c] = x[(size_t)c * HW + p];
}

// ---------------------------------------------------------------------------
// Per-box: adaptive 3x3 max-pool over the ROI per channel, fused dot with the
// collapsed weight vector w (length 2304), + collapsed bias, softplus.
// One block per box, one thread per channel. Reads xT (channel-fast) coalesced.
// ---------------------------------------------------------------------------
__global__ void roi_pool_dot(const float* __restrict__ xT, const int* __restrict__ det,
                             const float* __restrict__ wv, const float* __restrict__ cb,
                             float* __restrict__ out) {
    int n = blockIdx.x;
    int c = threadIdx.x;
    int x1 = det[n * 4 + 0], y1 = det[n * 4 + 1];
    int x2 = det[n * 4 + 2], y2 = det[n * 4 + 3];
    int hl = y2 - y1 + 1;
    int wl = x2 - x1 + 1;

    const float* wrow = wv + c * (OUTP * OUTP);
    float acc = 0.f;

    #pragma unroll
    for (int bi = 0; bi < OUTP; bi++) {
        int h0 = y1 + (bi * hl) / OUTP;
        int h1 = y1 + ((bi + 1) * hl + OUTP - 1) / OUTP;   // ceil
        #pragma unroll
        for (int bj = 0; bj < OUTP; bj++) {
            int w0 = x1 + (bj * wl) / OUTP;
            int w1 = x1 + ((bj + 1) * wl + OUTP - 1) / OUTP;
            float m = -INFINITY;
            for (int h = h0; h < h1; h++) {
                const float* rowp = xT + ((size_t)(h * W_DIM) ) * C_CH + c;
                for (int w = w0; w < w1; w++) {
                    m = fmaxf(m, rowp[(size_t)w * C_CH]);
                }
            }
            acc += m * wrow[bi * OUTP + bj];
        }
    }

    // block reduction over 256 threads (4 waves)
    __shared__ float red[4];
    #pragma unroll
    for (int off = 32; off; off >>= 1) acc += __shfl_down(acc, off, 64);
    int lane = threadIdx.x & 63, wid = threadIdx.x >> 6;
    if (lane == 0) red[wid] = acc;
    __syncthreads();
    if (threadIdx.x == 0) {
        float r = red[0] + red[1] + red[2] + red[3] + cb[0];
        // numerically stable softplus: max(r,0) + log1p(exp(-|r|))
        out[n] = fmaxf(r, 0.f) + log1pf(expf(-fabsf(r)));
    }
}

extern "C" void kernel_launch(void* const* d_in, const int* in_sizes, int n_in,
                              void* d_out, int out_size, void* d_ws, size_t ws_size,
                              hipStream_t stream) {
    const float* x   = (const float*)d_in[0];   // [1,256,26,26]
    const int*   det = (const int*)  d_in[1];   // [128,4]
    const float* W1  = (const float*)d_in[2];   // [2304,1024]
    const float* b1  = (const float*)d_in[3];   // [1024]
    const float* W2  = (const float*)d_in[4];   // [1024,512]
    const float* b2  = (const float*)d_in[5];   // [512]
    const float* W3  = (const float*)d_in[6];   // [512,1]
    const float* b3  = (const float*)d_in[7];   // [1]
    float* out = (float*)d_out;                 // [128]

    // workspace layout (floats)
    float* ws    = (float*)d_ws;
    float* xT    = ws;                   // 173056
    float* v     = xT + (size_t)HW * C_CH;   // 1024
    float* wvec  = v + H1;               // 2304
    float* cbias = wvec + FEAT;          // 1

    // 1) v = W2 @ W3   (R=1024, K=512) — 1024 waves -> 256 blocks of 256
    gemv_rows<<<(H1 * 64 + 255) / 256, 256, 0, stream>>>(W2, W3, v, H1, H2);

    // 2) w = W1 @ v    (R=2304, K=1024) — 2304 waves -> 576 blocks of 256
    gemv_rows<<<(FEAT * 64 + 255) / 256, 256, 0, stream>>>(W1, v, wvec, FEAT, H1);

    // 3) collapsed bias scalar
    bias_collapse<<<1, 256, 0, stream>>>(b1, v, b2, W3, b3, cbias);

    // 4) transpose x to channel-fast layout
    transpose_x<<<HW, C_CH, 0, stream>>>(x, xT);

    // 5) fused ROI adaptive maxpool + dot + softplus
    roi_pool_dot<<<N_BOX, C_CH, 0, stream>>>(xT, det, wvec, cbias, out);
}

// Round 2
// 26.882 us; speedup vs baseline: 3.5491x; 3.5491x over previous
//
#include <hip/hip_runtime.h>
#include <hip/hip_bf16.h>
#include <math.h>

// Problem constants
#define C_CH   256
#define H_DIM  26
#define W_DIM  26
#define HW     (H_DIM * W_DIM)      // 676
#define N_BOX  128
#define OUTP   3
#define NBIN   (OUTP * OUTP)        // 9
#define FEAT   (C_CH * NBIN)        // 2304
#define H1     1024
#define H2     512

#define GEMV2_BLOCKS (FEAT / 4)     // 576 blocks, 4 waves (rows) each

// ---------------------------------------------------------------------------
// Wave-per-row GEMV with float4 loads: out[r] = dot(M[r,:], v). K % 256 == 0.
// ---------------------------------------------------------------------------
__device__ __forceinline__ float gemv_row_f4(const float* __restrict__ M,
                                             const float* __restrict__ v,
                                             int r, int K, int lane) {
    const float4* row = (const float4*)(M + (size_t)r * K);
    const float4* vv  = (const float4*)v;
    float s = 0.f;
    for (int k4 = lane; k4 < (K >> 2); k4 += 64) {
        float4 a = row[k4], b = vv[k4];
        s += a.x * b.x + a.y * b.y + a.z * b.z + a.w * b.w;
    }
    #pragma unroll
    for (int off = 32; off; off >>= 1) s += __shfl_down(s, off, 64);
    return s;
}

// K1: v = W2 @ W3   (1024 rows of 512)
__global__ void gemv_w2(const float* __restrict__ W2, const float* __restrict__ w3,
                        float* __restrict__ v) {
    int r = blockIdx.x * 4 + (threadIdx.x >> 6);
    int lane = threadIdx.x & 63;
    float s = gemv_row_f4(W2, w3, r, H2, lane);
    if (lane == 0) v[r] = s;
}

// K2: wvec = W1 @ v  (2304 rows of 1024)  fused with  xT transpose (independent)
__global__ void gemv_w1_transpose(const float* __restrict__ W1, const float* __restrict__ v,
                                  float* __restrict__ wvec,
                                  const float* __restrict__ x, float* __restrict__ xT) {
    if (blockIdx.x < GEMV2_BLOCKS) {
        int r = blockIdx.x * 4 + (threadIdx.x >> 6);
        int lane = threadIdx.x & 63;
        float s = gemv_row_f4(W1, v, r, H1, lane);
        if (lane == 0) wvec[r] = s;
    } else {
        int p = blockIdx.x - GEMV2_BLOCKS;   // pixel 0..675
        int c = threadIdx.x;                 // channel
        xT[p * C_CH + c] = x[(size_t)c * HW + p];
    }
}

// K3: per-(box,bin) partial dot. One block per (n,bin); one thread per channel.
__global__ void roi_partial(const float* __restrict__ xT, const int* __restrict__ det,
                            const float* __restrict__ wv, float* __restrict__ partials) {
    int nb = blockIdx.x;
    int n = nb / NBIN, bin = nb - n * NBIN;
    int bi = bin / OUTP, bj = bin - bi * OUTP;
    int c = threadIdx.x;

    int x1 = det[n * 4 + 0], y1 = det[n * 4 + 1];
    int x2 = det[n * 4 + 2], y2 = det[n * 4 + 3];
    int hl = y2 - y1 + 1, wl = x2 - x1 + 1;

    int h0 = y1 + (bi * hl) / OUTP;
    int h1 = y1 + ((bi + 1) * hl + OUTP - 1) / OUTP;
    int w0 = x1 + (bj * wl) / OUTP;
    int w1 = x1 + ((bj + 1) * wl + OUTP - 1) / OUTP;

    float m = -INFINITY;
    for (int h = h0; h < h1; h++) {
        const float* rowp = xT + (size_t)(h * W_DIM) * C_CH + c;
        for (int w = w0; w < w1; w++)
            m = fmaxf(m, rowp[(size_t)w * C_CH]);
    }
    float acc = m * wv[c * NBIN + bin];

    #pragma unroll
    for (int off = 32; off; off >>= 1) acc += __shfl_down(acc, off, 64);
    __shared__ float red[4];
    int lane = threadIdx.x & 63, wid = threadIdx.x >> 6;
    if (lane == 0) red[wid] = acc;
    __syncthreads();
    if (threadIdx.x == 0) partials[nb] = red[0] + red[1] + red[2] + red[3];
}

// K4: cbias = b1.v + b2.w3 + b3; out[n] = softplus(sum_bin partials[n,bin] + cbias)
__global__ void finalize(const float* __restrict__ b1, const float* __restrict__ v,
                         const float* __restrict__ b2, const float* __restrict__ w3,
                         const float* __restrict__ b3, const float* __restrict__ partials,
                         float* __restrict__ out) {
    int t = threadIdx.x;
    float s = 0.f;
    for (int k = t; k < H1; k += 256) s += b1[k] * v[k];
    for (int k = t; k < H2; k += 256) s += b2[k] * w3[k];
    #pragma unroll
    for (int off = 32; off; off >>= 1) s += __shfl_down(s, off, 64);
    __shared__ float red[4];
    __shared__ float cb;
    int lane = t & 63, wid = t >> 6;
    if (lane == 0) red[wid] = s;
    __syncthreads();
    if (t == 0) cb = red[0] + red[1] + red[2] + red[3] + b3[0];
    __syncthreads();
    if (t < N_BOX) {
        float r = cb;
        #pragma unroll
        for (int j = 0; j < NBIN; j++) r += partials[t * NBIN + j];
        out[t] = fmaxf(r, 0.f) + log1pf(expf(-fabsf(r)));   // stable softplus
    }
}

extern "C" void kernel_launch(void* const* d_in, const int* in_sizes, int n_in,
                              void* d_out, int out_size, void* d_ws, size_t ws_size,
                              hipStream_t stream) {
    const float* x   = (const float*)d_in[0];
    const int*   det = (const int*)  d_in[1];
    const float* W1  = (const float*)d_in[2];
    const float* b1  = (const float*)d_in[3];
    const float* W2  = (const float*)d_in[4];
    const float* b2  = (const float*)d_in[5];
    const float* W3  = (const float*)d_in[6];
    const float* b3  = (const float*)d_in[7];
    float* out = (float*)d_out;

    float* ws       = (float*)d_ws;
    float* xT       = ws;                          // 173056 floats
    float* v        = xT + (size_t)HW * C_CH;      // 1024
    float* wvec     = v + H1;                      // 2304
    float* partials = wvec + FEAT;                 // 1152

    // K1: v = W2 @ W3
    gemv_w2<<<H1 / 4, 256, 0, stream>>>(W2, W3, v);

    // K2: wvec = W1 @ v  (blocks 0..575) + transpose x (blocks 576..1251)
    gemv_w1_transpose<<<GEMV2_BLOCKS + HW, 256, 0, stream>>>(W1, v, wvec, x, xT);

    // K3: per-(box,bin) pooled partial dot products
    roi_partial<<<N_BOX * NBIN, 256, 0, stream>>>(xT, det, wvec, partials);

    // K4: collapsed bias + per-box sum + softplus
    finalize<<<1, 256, 0, stream>>>(b1, v, b2, W3, b3, partials, out);
}

// Round 3
// 23.456 us; speedup vs baseline: 4.0675x; 1.1461x over previous
//
#include <hip/hip_runtime.h>
#include <hip/hip_bf16.h>
#include <math.h>

// Problem constants
#define C_CH   256
#define H_DIM  26
#define W_DIM  26
#define HW     (H_DIM * W_DIM)      // 676
#define N_BOX  128
#define OUTP   3
#define NBIN   (OUTP * OUTP)        // 9
#define FEAT   (C_CH * NBIN)        // 2304
#define H1     1024
#define H2     512

#define KA_GEMV_BLOCKS (H1 / 4)     // 256 blocks, 4 rows (waves) each
#define KB_GEMV_BLOCKS (FEAT / 4)   // 576 blocks
#define KB_ROI_BLOCKS  (N_BOX * NBIN) // 1152

// ---------------------------------------------------------------------------
// Wave-per-row GEMV with float4 loads: dot(M[r,:], v). K % 256 == 0.
// ---------------------------------------------------------------------------
__device__ __forceinline__ float gemv_row_f4(const float* __restrict__ M,
                                             const float* __restrict__ v,
                                             int r, int K, int lane) {
    const float4* row = (const float4*)(M + (size_t)r * K);
    const float4* vv  = (const float4*)v;
    float s = 0.f;
    for (int k4 = lane; k4 < (K >> 2); k4 += 64) {
        float4 a = row[k4], b = vv[k4];
        s += a.x * b.x + a.y * b.y + a.z * b.z + a.w * b.w;
    }
    #pragma unroll
    for (int off = 32; off; off >>= 1) s += __shfl_down(s, off, 64);
    return s;
}

// ---------------------------------------------------------------------------
// K_A: v = W2 @ W3 (blocks 0..255) || transpose x -> xT [pixel][channel]
// ---------------------------------------------------------------------------
__global__ void kA(const float* __restrict__ W2, const float* __restrict__ w3,
                   float* __restrict__ v,
                   const float* __restrict__ x, float* __restrict__ xT) {
    if (blockIdx.x < KA_GEMV_BLOCKS) {
        int r = blockIdx.x * 4 + (threadIdx.x >> 6);
        int lane = threadIdx.x & 63;
        float s = gemv_row_f4(W2, w3, r, H2, lane);
        if (lane == 0) v[r] = s;
    } else {
        int p = blockIdx.x - KA_GEMV_BLOCKS;    // pixel 0..675
        xT[p * C_CH + threadIdx.x] = x[(size_t)threadIdx.x * HW + p];
    }
}

// ---------------------------------------------------------------------------
// K_B: wvec2[bin*256+c] = dot(W1[c*9+bin,:], v)   (blocks 0..575)
//   || feats[n][bin*256+c] = ROI-bin max          (blocks 576..1727)
//   || cb = b1.v + b2.w3 + b3                     (block 1728)
// ---------------------------------------------------------------------------
__global__ void kB(const float* __restrict__ W1, const float* __restrict__ v,
                   float* __restrict__ wvec2,
                   const float* __restrict__ xT, const int* __restrict__ det,
                   float* __restrict__ feats,
                   const float* __restrict__ b1, const float* __restrict__ b2,
                   const float* __restrict__ w3, const float* __restrict__ b3,
                   float* __restrict__ cb) {
    int b = blockIdx.x;
    if (b < KB_GEMV_BLOCKS) {
        int r = b * 4 + (threadIdx.x >> 6);      // r = c*9 + bin
        int lane = threadIdx.x & 63;
        float s = gemv_row_f4(W1, v, r, H1, lane);
        if (lane == 0) wvec2[(r % NBIN) * C_CH + (r / NBIN)] = s;
    } else if (b < KB_GEMV_BLOCKS + KB_ROI_BLOCKS) {
        int nb = b - KB_GEMV_BLOCKS;
        int n = nb / NBIN, bin = nb - n * NBIN;
        int bi = bin / OUTP, bj = bin - bi * OUTP;
        int c = threadIdx.x;

        int x1 = det[n * 4 + 0], y1 = det[n * 4 + 1];
        int x2 = det[n * 4 + 2], y2 = det[n * 4 + 3];
        int hl = y2 - y1 + 1, wl = x2 - x1 + 1;

        int h0 = y1 + (bi * hl) / OUTP;
        int h1e = y1 + ((bi + 1) * hl + OUTP - 1) / OUTP;
        int w0 = x1 + (bj * wl) / OUTP;
        int w1e = x1 + ((bj + 1) * wl + OUTP - 1) / OUTP;

        float m = -INFINITY;
        for (int h = h0; h < h1e; h++) {
            const float* rowp = xT + (size_t)(h * W_DIM) * C_CH + c;
            for (int w = w0; w < w1e; w++)
                m = fmaxf(m, rowp[(size_t)w * C_CH]);
        }
        feats[(size_t)n * FEAT + bin * C_CH + c] = m;   // coalesced 1KB store
    } else {
        // collapsed bias
        int t = threadIdx.x;
        float s = 0.f;
        for (int k = t; k < H1; k += 256) s += b1[k] * v[k];
        for (int k = t; k < H2; k += 256) s += b2[k] * w3[k];
        #pragma unroll
        for (int off = 32; off; off >>= 1) s += __shfl_down(s, off, 64);
        __shared__ float red[4];
        int lane = t & 63, wid = t >> 6;
        if (lane == 0) red[wid] = s;
        __syncthreads();
        if (t == 0) cb[0] = red[0] + red[1] + red[2] + red[3] + b3[0];
    }
}

// ---------------------------------------------------------------------------
// K_C: out[n] = softplus(dot(feats[n], wvec2) + cb)
// ---------------------------------------------------------------------------
__global__ void kC(const float* __restrict__ feats, const float* __restrict__ wvec2,
                   const float* __restrict__ cb, float* __restrict__ out) {
    int n = blockIdx.x, t = threadIdx.x;
    const float* f = feats + (size_t)n * FEAT;
    float s = 0.f;
    #pragma unroll
    for (int j = 0; j < NBIN; j++) s += f[j * C_CH + t] * wvec2[j * C_CH + t];
    #pragma unroll
    for (int off = 32; off; off >>= 1) s += __shfl_down(s, off, 64);
    __shared__ float red[4];
    int lane = t & 63, wid = t >> 6;
    if (lane == 0) red[wid] = s;
    __syncthreads();
    if (t == 0) {
        float r = red[0] + red[1] + red[2] + red[3] + cb[0];
        out[n] = fmaxf(r, 0.f) + log1pf(expf(-fabsf(r)));   // stable softplus
    }
}

extern "C" void kernel_launch(void* const* d_in, const int* in_sizes, int n_in,
                              void* d_out, int out_size, void* d_ws, size_t ws_size,
                              hipStream_t stream) {
    const float* x   = (const float*)d_in[0];
    const int*   det = (const int*)  d_in[1];
    const float* W1  = (const float*)d_in[2];
    const float* b1  = (const float*)d_in[3];
    const float* W2  = (const float*)d_in[4];
    const float* b2  = (const float*)d_in[5];
    const float* W3  = (const float*)d_in[6];
    const float* b3  = (const float*)d_in[7];
    float* out = (float*)d_out;

    float* ws    = (float*)d_ws;
    float* xT    = ws;                              // 173056 floats
    float* v     = xT + (size_t)HW * C_CH;          // 1024
    float* wvec2 = v + H1;                          // 2304 (bin-major)
    float* feats = wvec2 + FEAT;                    // 128*2304 = 294912
    float* cb    = feats + (size_t)N_BOX * FEAT;    // 1

    kA<<<KA_GEMV_BLOCKS + HW, 256, 0, stream>>>(W2, W3, v, x, xT);
    kB<<<KB_GEMV_BLOCKS + KB_ROI_BLOCKS + 1, 256, 0, stream>>>(
        W1, v, wvec2, xT, det, feats, b1, b2, W3, b3, cb);
    kC<<<N_BOX, 256, 0, stream>>>(feats, wvec2, cb, out);
}